// Round 3
// baseline (424.451 us; speedup 1.0000x reference)
//
#include <hip/hip_runtime.h>
#include <hip/hip_bf16.h>
#include <stdint.h>

#define N_NODES 50000
#define N_EDGES 1600000
#define D_IN    512
#define D_H1    256   // 4 heads * 64 concat
#define D_OUT   64

#define NBUK    196   // coarse buckets: src>>8 (256 nodes each)
#define MAXB    9216  // per-bucket region capacity (mean 8163, +11 sigma)
#define EPB     4096  // edges per partition block
#define NPB     391   // ceil(N_EDGES / EPB)
#define SLOT    96    // per-node list stride (max degree ~58 for Poisson(32), padded to mult-8)

#define NR      50001 // rows per slice incl. zero row
#define ZROW    50000 // reserved all-zero row index (pad target)

typedef __attribute__((ext_vector_type(8))) short  short8;   // 8 bf16 = 4 VGPRs (MFMA A/B frag)
typedef __attribute__((ext_vector_type(4))) float  f32x4;    // MFMA C/D frag
typedef __attribute__((ext_vector_type(2))) float  f32x2;    // packed f32 pair (v_pk_add_f32)
typedef __attribute__((ext_vector_type(4))) unsigned int u32x4;
typedef __attribute__((ext_vector_type(2))) unsigned int u32x2;

// address-space-qualified void for the global_load_lds builtin
typedef __attribute__((address_space(1))) void GASV;
typedef __attribute__((address_space(3))) void LASV;

static __device__ __forceinline__ unsigned short f2bf(float f) {
    union { float f; unsigned int u; } c; c.f = f;
    unsigned int u = c.u;
    return (unsigned short)((u + 0x7FFFu + ((u >> 16) & 1u)) >> 16);  // RNE
}
static __device__ __forceinline__ float uasf(unsigned int u) {
    union { unsigned int u; float f; } c; c.u = u; return c.f;
}

// ---------------- phase 1: partition edges into 196 coarse buckets ----------------

__global__ __launch_bounds__(256) void part_kernel(const int* __restrict__ src,
                                                   const int* __restrict__ dst,
                                                   int* __restrict__ gcnt,
                                                   unsigned int* __restrict__ gbuk) {
    __shared__ int hist[NBUK];
    __shared__ int lofs[NBUK];          // exclusive offsets in sorted[]
    __shared__ int gbase[NBUK];         // this block's reservation in bucket region
    __shared__ int sbuf[256];
    __shared__ unsigned int sorted[EPB];
    __shared__ unsigned char bid[EPB];

    const int t  = threadIdx.x;
    const int e0 = blockIdx.x * EPB;
    int ec = N_EDGES - e0; if (ec > EPB) ec = EPB;

    for (int i = t; i < NBUK; i += 256) hist[i] = 0;
    __syncthreads();

    unsigned int rec[16];
    int bb[16], idx[16];
#pragma unroll
    for (int j = 0; j < 16; ++j) {
        int i = j * 256 + t;
        if (i < ec) {
            int s = src[e0 + i], d = dst[e0 + i];
            int b = s >> 8;
            rec[j] = ((unsigned int)(s & 255) << 16) | (unsigned int)d;
            bb[j]  = b;
            idx[j] = atomicAdd(&hist[b], 1);
        } else bb[j] = -1;
    }
    __syncthreads();

    // inclusive scan of hist over 256 slots (entries >= NBUK are 0)
    int v = (t < NBUK) ? hist[t] : 0;
    sbuf[t] = v;
    __syncthreads();
#pragma unroll
    for (int off = 1; off < 256; off <<= 1) {
        int x = (t >= off) ? sbuf[t - off] : 0;
        __syncthreads();
        sbuf[t] += x;
        __syncthreads();
    }
    if (t < NBUK) {
        lofs[t]  = sbuf[t] - v;                 // exclusive
        gbase[t] = atomicAdd(&gcnt[t], v);      // one global atomic per bucket per block
    }
    __syncthreads();

#pragma unroll
    for (int j = 0; j < 16; ++j) {
        if (bb[j] >= 0) {
            int p = lofs[bb[j]] + idx[j];
            sorted[p] = rec[j];
            bid[p] = (unsigned char)bb[j];
        }
    }
    __syncthreads();

    for (int i = t; i < ec; i += 256) {
        int b = bid[i];
        int p = gbase[b] + (i - lofs[b]);
        gbuk[(size_t)b * MAXB + p] = sorted[i];
    }
}

// ---------------- phase 2: per-bucket LDS counting sort -> per-node padded lists ----------------

__global__ __launch_bounds__(256) void sort_kernel(const int* __restrict__ gcnt,
                                                   const unsigned int* __restrict__ gbuk,
                                                   unsigned short* __restrict__ sdst,
                                                   int* __restrict__ deg) {
    __shared__ int hist[256];
    __shared__ int nofs[256];           // exclusive offsets, used as running cursors
    __shared__ int sbuf[256];
    __shared__ unsigned short list[MAXB];

    const int t = threadIdx.x;
    const int b = blockIdx.x;
    const int cnt = gcnt[b];
    const unsigned int* buk = gbuk + (size_t)b * MAXB;

    hist[t] = 0;
    __syncthreads();
    for (int i = t; i < cnt; i += 256)
        atomicAdd(&hist[buk[i] >> 16], 1);
    __syncthreads();

    int v = hist[t];
    sbuf[t] = v;
    __syncthreads();
#pragma unroll
    for (int off = 1; off < 256; off <<= 1) {
        int x = (t >= off) ? sbuf[t - off] : 0;
        __syncthreads();
        sbuf[t] += x;
        __syncthreads();
    }
    nofs[t] = sbuf[t] - v;              // exclusive
    const int n = b * 256 + t;
    if (n < N_NODES) deg[n] = v;
    __syncthreads();

    for (int i = t; i < cnt; i += 256) {
        unsigned int r = buk[i];
        int p = atomicAdd(&nofs[r >> 16], 1);
        list[p] = (unsigned short)(r & 0xffffu);
    }
    __syncthreads();

    if (n < N_NODES) {
        int beg = nofs[t] - v;          // nofs is now inclusive end
        unsigned short* out = sdst + (size_t)n * SLOT;
        for (int j = 0; j < v; ++j) out[j] = list[beg + j];
        int pc = (v + 7) & ~7;          // pad to mult-8 with zero-row index
        for (int j = v; j < pc; ++j) out[j] = (unsigned short)ZROW;
    }
}

// ---------------- weight repack + zero-row init ----------------

__global__ void convw_kernel(const float* __restrict__ W1, const float* __restrict__ W2,
                             unsigned short* __restrict__ Bt1, unsigned short* __restrict__ Bt2,
                             unsigned short* __restrict__ t1, unsigned short* __restrict__ t2) {
    int i = blockIdx.x * 256 + threadIdx.x;
    if (i < 4 * 512 * 64) {                 // W1[h][k][j] -> Bt1[(h*64+j)][k]
        int h = i >> 15;
        int k = (i >> 6) & 511;
        int j = i & 63;
        Bt1[(h * 64 + j) * 512 + k] = f2bf(W1[i]);
    } else if (i < 4 * 512 * 64 + 256 * 64) {
        int r = i - 4 * 512 * 64;           // W2[k][n] -> Bt2[n][k]
        int k = r >> 6;
        int n = r & 63;
        Bt2[n * 256 + k] = f2bf(W2[r]);
    } else {
        int r = i - (4 * 512 * 64 + 256 * 64);
        if (r < 8 * 32) {                   // zero row of each t1 slice
            t1[(size_t)(r >> 5) * ((size_t)NR * 32) + (size_t)ZROW * 32 + (r & 31)] = 0;
        } else if (r < 8 * 32 + 2 * 32) {   // zero row of each t2 slice
            int q = r - 8 * 32;
            t2[(size_t)(q >> 5) * ((size_t)NR * 32) + (size_t)ZROW * 32 + (q & 31)] = 0;
        }
    }
}

// ---------------- GEMM1: t1s[8][NR][32] = slice-major( X[M][512] @ Bt1[256][512]^T ) ----------------
// BM=128, BN=256 (A read once), block=512 (8 waves 2x4), wave tile 64x64, BK=32.

__global__ __launch_bounds__(512) void gemm1_kernel(const float* __restrict__ A,
                                                    const unsigned short* __restrict__ Bt,
                                                    unsigned short* __restrict__ C) {
    constexpr int BM = 128, BK = 32, LDK = 40, K = D_IN, M = N_NODES;
    __shared__ unsigned short As[BM * LDK];   // 10.0 KB
    __shared__ unsigned short Bs[256 * LDK];  // 20.0 KB

    const int tid  = threadIdx.x;
    const int lane = tid & 63;
    const int w    = tid >> 6;
    const int wm   = (w >> 2) * 64;
    const int wn   = (w & 3) * 64;
    const int quad = lane >> 4;
    const int l15  = lane & 15;
    const int bm   = blockIdx.x;

    f32x4 acc[4][4];
#pragma unroll
    for (int mi = 0; mi < 4; ++mi)
#pragma unroll
        for (int ni = 0; ni < 4; ++ni)
            acc[mi][ni] = (f32x4){0.f, 0.f, 0.f, 0.f};

    const int r0 = tid >> 2;      // 0..127
    const int f8 = tid & 3;       // 8-elem chunk within a 32-col row

    for (int k0 = 0; k0 < K; k0 += BK) {
        {   // stage A (128 x 32 fp32 -> bf16), 8 floats per thread
            int grow = bm * BM + r0;
            if (grow >= M) grow = M - 1;
            const float* ap = A + (size_t)grow * K + k0 + f8 * 8;
            f32x4 v0 = *(const f32x4*)ap;
            f32x4 v1 = *(const f32x4*)(ap + 4);
            u32x4 pk;
            pk[0] = (unsigned int)f2bf(v0[0]) | ((unsigned int)f2bf(v0[1]) << 16);
            pk[1] = (unsigned int)f2bf(v0[2]) | ((unsigned int)f2bf(v0[3]) << 16);
            pk[2] = (unsigned int)f2bf(v1[0]) | ((unsigned int)f2bf(v1[1]) << 16);
            pk[3] = (unsigned int)f2bf(v1[2]) | ((unsigned int)f2bf(v1[3]) << 16);
            *(u32x4*)&As[r0 * LDK + f8 * 8] = pk;
        }
        {   // stage B (256 x 32 bf16), two u32x4 per thread
#pragma unroll
            for (int p = 0; p < 2; ++p) {
                int row = p * 128 + r0;
                u32x4 v = *(const u32x4*)(Bt + (size_t)row * K + k0 + f8 * 8);
                *(u32x4*)&Bs[row * LDK + f8 * 8] = v;
            }
        }
        __syncthreads();

        short8 af[4], bfr[4];
#pragma unroll
        for (int mi = 0; mi < 4; ++mi)
            af[mi] = *(const short8*)&As[(wm + mi * 16 + l15) * LDK + quad * 8];
#pragma unroll
        for (int ni = 0; ni < 4; ++ni)
            bfr[ni] = *(const short8*)&Bs[(wn + ni * 16 + l15) * LDK + quad * 8];
#pragma unroll
        for (int mi = 0; mi < 4; ++mi)
#pragma unroll
            for (int ni = 0; ni < 4; ++ni)
                acc[mi][ni] = __builtin_amdgcn_mfma_f32_16x16x32_bf16(af[mi], bfr[ni], acc[mi][ni], 0, 0, 0);
        __syncthreads();
    }

    // epilogue: slice-major store  t1s[col>>5][row][col&31]
#pragma unroll
    for (int mi = 0; mi < 4; ++mi) {
        int row0 = bm * BM + wm + mi * 16 + quad * 4;
#pragma unroll
        for (int ni = 0; ni < 4; ++ni) {
            int col = wn + ni * 16 + l15;
            unsigned short* cp = C + (size_t)(col >> 5) * ((size_t)NR * 32) + (col & 31);
#pragma unroll
            for (int r = 0; r < 4; ++r) {
                int row = row0 + r;
                if (row < M) cp[(size_t)row * 32] = f2bf(acc[mi][ni][r]);
            }
        }
    }
}

// ---------------- GEMM2: t2s[2][NR][32] = slice-major( h[M][256](bf16) @ Bt2[64][256]^T ) ----------------

__global__ __launch_bounds__(256) void gemm2_kernel(const unsigned short* __restrict__ A,
                                                    const unsigned short* __restrict__ Bt,
                                                    unsigned short* __restrict__ C) {
    constexpr int BM = 64, BK = 32, LDK = 40, K = D_H1, M = N_NODES;
    __shared__ unsigned short As[BM * LDK];
    __shared__ unsigned short Bs[64 * LDK];

    const int tid  = threadIdx.x;
    const int lane = tid & 63;
    const int w    = tid >> 6;
    const int wm   = (w >> 1) * 32;
    const int wn   = (w & 1) * 32;
    const int quad = lane >> 4;
    const int l15  = lane & 15;
    const int bm   = blockIdx.x;

    f32x4 acc[2][2];
#pragma unroll
    for (int mi = 0; mi < 2; ++mi)
#pragma unroll
        for (int ni = 0; ni < 2; ++ni)
            acc[mi][ni] = (f32x4){0.f, 0.f, 0.f, 0.f};

    for (int k0 = 0; k0 < K; k0 += BK) {
        {
            int f8 = tid & 3;
            int r0 = tid >> 2;
            int grow = bm * BM + r0;
            if (grow >= M) grow = M - 1;
            u32x4 v = *(const u32x4*)(A + (size_t)grow * K + k0 + f8 * 8);
            *(u32x4*)&As[r0 * LDK + f8 * 8] = v;
        }
        {
            int f8 = tid & 3;
            int r0 = tid >> 2;
            u32x4 v = *(const u32x4*)(Bt + (size_t)r0 * K + k0 + f8 * 8);
            *(u32x4*)&Bs[r0 * LDK + f8 * 8] = v;
        }
        __syncthreads();

        short8 af[2], bfr[2];
#pragma unroll
        for (int mi = 0; mi < 2; ++mi)
            af[mi] = *(const short8*)&As[(wm + mi * 16 + l15) * LDK + quad * 8];
#pragma unroll
        for (int ni = 0; ni < 2; ++ni)
            bfr[ni] = *(const short8*)&Bs[(wn + ni * 16 + l15) * LDK + quad * 8];
#pragma unroll
        for (int mi = 0; mi < 2; ++mi)
#pragma unroll
            for (int ni = 0; ni < 2; ++ni)
                acc[mi][ni] = __builtin_amdgcn_mfma_f32_16x16x32_bf16(af[mi], bfr[ni], acc[mi][ni], 0, 0, 0);
        __syncthreads();
    }

#pragma unroll
    for (int mi = 0; mi < 2; ++mi) {
        int row0 = bm * BM + wm + mi * 16 + quad * 4;
#pragma unroll
        for (int ni = 0; ni < 2; ++ni) {
            int col = wn + ni * 16 + l15;
            unsigned short* cp = C + (size_t)(col >> 5) * ((size_t)NR * 32) + (col & 31);
#pragma unroll
            for (int r = 0; r < 4; ++r) {
                int row = row0 + r;
                if (row < M) cp[(size_t)row * 32] = f2bf(acc[mi][ni][r]);
            }
        }
    }
}

// ---------------- aggregation ----------------
// agg1 v3: XCD-pinned slices (proven: FETCH 346->52 MB) + DMA gather via
// global_load_lds. Rounds 1-2 showed the per-lane gather path saturates at
// ~8.3 B/cy/CU regardless of width/instruction count -> per-CU miss-tracking cap.
// The DMA path sustains deep vmcnt queues (GEMM evidence); per-lane global
// address + wave-uniform LDS dest (base + lane*4) is HW-verified. Per node:
// issue all K<=16 gather-DMAs (4 rows/256B each), one vmcnt(0), consume from LDS.

__global__ __launch_bounds__(256) void agg1_kernel(const unsigned short* __restrict__ t,
                                                   const int* __restrict__ deg,
                                                   const unsigned short* __restrict__ sdst,
                                                   unsigned short* __restrict__ h) {
    __shared__ unsigned int ring[4][16 * 64];   // per wave: 16 slots x 256B = 4KB
    const int bi    = blockIdx.x;
    const int slice = bi & 7;
    const int g     = bi >> 3;
    const int w     = __builtin_amdgcn_readfirstlane(threadIdx.x >> 6);
    const int lane  = threadIdx.x & 63;
    const int sub   = lane >> 4;                // 4 rows per DMA
    const int cc    = lane & 15;                // u32 chunk: cols 2cc, 2cc+1
    unsigned int* ringw = &ring[w][0];
    const unsigned int* tb32 = (const unsigned int*)(t + (size_t)slice * ((size_t)NR * 32));

    const int s0 = g * 16 + w * 4;
    int end_[4], elv_[4];
#pragma unroll
    for (int j = 0; j < 4; ++j) {               // prefetch degree + whole edge list (<=64)
        end_[j] = __builtin_nontemporal_load(deg + s0 + j);
        elv_[j] = (int)__builtin_nontemporal_load(sdst + (size_t)(s0 + j) * SLOT + lane);
    }

#pragma unroll
    for (int j = 0; j < 4; ++j) {
        const int s   = s0 + j;
        const int end = end_[j];
        const int K   = ((end + 7) & ~7) >> 2;  // pc/4, <= 16 (deg <= 58 padded to mult-8)
        const int elv = elv_[j];

        for (int k = 0; k < K; ++k) {           // issue phase: K independent gather-DMAs
            int row = __shfl(elv, 4 * k + sub);
            const unsigned int* gp = tb32 + ((unsigned)row << 4) + cc;
            __builtin_amdgcn_global_load_lds((GASV*)gp, (LASV*)(ringw + (k << 6)), 4, 0, 0);
        }
        asm volatile("s_waitcnt vmcnt(0)" ::: "memory");
        __builtin_amdgcn_sched_barrier(0);

        f32x2 A = {0.f, 0.f};
        for (int k = 0; k < K; ++k) {           // consume phase (own lane's u32 per slot)
            unsigned int v = ringw[(k << 6) + lane];
            f32x2 x;
            x.x = uasf(v << 16); x.y = uasf(v & 0xffff0000u);
            A += x;
        }
        f32x2 B;
        B.x = __shfl_xor(A.x, 16); B.y = __shfl_xor(A.y, 16); A += B;
        B.x = __shfl_xor(A.x, 32); B.y = __shfl_xor(A.y, 32); A += B;
        if (sub == 0) {
            float iv = (end > 0) ? (1.0f / (float)end) : 0.f;
            float m0 = A.x * iv, m1 = A.y * iv;
            m0 = (m0 > 0.f) ? m0 : (__expf(m0) - 1.f);
            m1 = (m1 > 0.f) ? m1 : (__expf(m1) - 1.f);
            unsigned int pk;
            asm("v_cvt_pk_bf16_f32 %0, %1, %2" : "=v"(pk) : "v"(m0), "v"(m1));
            *(unsigned int*)&h[(size_t)s * D_H1 + slice * 32 + cc * 2] = pk;
        }
    }
}

// agg2: paired experiment — round-2 per-lane gather structure, but row gathers are
// nontemporal (tests the L1-allocation-contention theory on the same access pattern).

__global__ __launch_bounds__(256) void agg2_kernel(const unsigned short* __restrict__ t2,
                                                   const int* __restrict__ deg,
                                                   const unsigned short* __restrict__ sdst,
                                                   float* __restrict__ out) {
    const int bi    = blockIdx.x;
    const int slice = bi & 1;
    const int g     = bi >> 1;
    const int w     = __builtin_amdgcn_readfirstlane(threadIdx.x >> 6);
    const int lane  = threadIdx.x & 63;
    const int sub   = lane >> 4;
    const int cc    = lane & 15;
    const int cc2   = cc * 2;
    const unsigned short* tb = t2 + (size_t)slice * ((size_t)NR * 32);

#pragma unroll
    for (int j = 0; j < 4; ++j) {
        const int s   = g * 16 + w * 4 + j;
        const int end = deg[s];
        const int pc  = (end + 7) & ~7;
        const unsigned short* el = sdst + (size_t)s * SLOT + 2 * sub;
        f32x2 A = {0.f, 0.f};
        for (int e = 0; e < pc; e += 8) {
            unsigned int wp = *(const unsigned int*)(el + e);
            unsigned int o0 = (wp & 0xffffu) * 32u + cc2;
            unsigned int o1 = (wp >> 16) * 32u + cc2;
            unsigned int v0 = __builtin_nontemporal_load((const unsigned int*)(tb + o0));
            unsigned int v1 = __builtin_nontemporal_load((const unsigned int*)(tb + o1));
            f32x2 x0, x1;
            x0.x = uasf(v0 << 16); x0.y = uasf(v0 & 0xffff0000u);
            x1.x = uasf(v1 << 16); x1.y = uasf(v1 & 0xffff0000u);
            A += x0;
            A += x1;
        }
        f32x2 B;
        B.x = __shfl_xor(A.x, 16); B.y = __shfl_xor(A.y, 16); A += B;
        B.x = __shfl_xor(A.x, 32); B.y = __shfl_xor(A.y, 32); A += B;
        if (sub == 0) {
            float iv = (end > 0) ? (1.0f / (float)end) : 0.f;
            f32x2 r; r.x = A.x * iv; r.y = A.y * iv;
            *(f32x2*)(out + (size_t)s * D_OUT + slice * 32 + cc2) = r;
        }
    }
}

// ---------------- launch ----------------

extern "C" void kernel_launch(void* const* d_in, const int* in_sizes, int n_in,
                              void* d_out, int out_size, void* d_ws, size_t ws_size,
                              hipStream_t stream) {
    const float* X  = (const float*)d_in[0];
    const int*   ei = (const int*)d_in[1];
    const float* W1 = (const float*)d_in[2];
    const float* W2 = (const float*)d_in[3];
    const int* src = ei;             // edge_index[0] = segment ids
    const int* dst = ei + N_EDGES;   // edge_index[1] = gathered neighbors

    char* ws = (char*)d_ws;
    size_t off = 0;
    auto alloc = [&](size_t bytes) {
        off = (off + 255) & ~(size_t)255;
        void* p = ws + off;
        off += bytes;
        return p;
    };
    int*          gcnt = (int*)alloc((size_t)NBUK * 4);
    unsigned int* gbuk = (unsigned int*)alloc((size_t)NBUK * MAXB * 4);
    unsigned short* sdst = (unsigned short*)alloc(((size_t)N_NODES * SLOT + 64) * 2);
    int*          deg  = (int*)alloc((size_t)N_NODES * 4);
    unsigned short* Bt1 = (unsigned short*)alloc((size_t)D_H1 * D_IN * 2);
    unsigned short* Bt2 = (unsigned short*)alloc((size_t)D_OUT * D_H1 * 2);
    unsigned short* t1  = (unsigned short*)alloc((size_t)8 * NR * 32 * 2);
    unsigned short* h   = (unsigned short*)alloc((size_t)N_NODES * D_H1 * 2);
    unsigned short* t2  = (unsigned short*)alloc((size_t)2 * NR * 32 * 2);

    hipMemsetAsync(gcnt, 0, (size_t)NBUK * 4, stream);

    part_kernel<<<NPB, 256, 0, stream>>>(src, dst, gcnt, gbuk);
    sort_kernel<<<NBUK, 256, 0, stream>>>(gcnt, gbuk, sdst, deg);
    convw_kernel<<<(4 * 512 * 64 + 256 * 64 + 8 * 32 + 2 * 32 + 255) / 256, 256, 0, stream>>>(
        W1, W2, Bt1, Bt2, t1, t2);

    gemm1_kernel<<<(N_NODES + 127) / 128, 512, 0, stream>>>(X, Bt1, t1);
    agg1_kernel<<<(N_NODES / 16) * 8, 256, 0, stream>>>(t1, deg, sdst, h);
    gemm2_kernel<<<(N_NODES + 63) / 64, 256, 0, stream>>>(h, Bt2, t2);
    agg2_kernel<<<(N_NODES / 16) * 2, 256, 0, stream>>>(t2, deg, sdst, (float*)d_out);
}

// Round 4
// 370.716 us; speedup vs baseline: 1.1449x; 1.1449x over previous
//
#include <hip/hip_runtime.h>
#include <hip/hip_bf16.h>
#include <stdint.h>

#define N_NODES 50000
#define N_EDGES 1600000
#define D_IN    512
#define D_H1    256   // 4 heads * 64 concat
#define D_OUT   64

#define NBUK    196   // coarse buckets: src>>8 (256 nodes each)
#define MAXB    9216  // per-bucket region capacity (mean 8163, +11 sigma)
#define EPB     4096  // edges per partition block
#define NPB     391   // ceil(N_EDGES / EPB)
#define SLOT    96    // per-node list stride (max degree ~58, padded to mult-16)

#define NR      50001 // rows per slice incl. zero row
#define ZROW    50000 // reserved all-zero row index (pad target)

typedef __attribute__((ext_vector_type(8))) short  short8;   // 8 bf16 = 4 VGPRs (MFMA A/B frag)
typedef __attribute__((ext_vector_type(4))) float  f32x4;    // MFMA C/D frag
typedef __attribute__((ext_vector_type(2))) float  f32x2;
typedef __attribute__((ext_vector_type(4))) unsigned int u32x4;
typedef __attribute__((ext_vector_type(2))) unsigned int u32x2;

// address-space-qualified void for the global_load_lds builtin
typedef __attribute__((address_space(1))) void GASV;
typedef __attribute__((address_space(3))) void LASV;

static __device__ __forceinline__ unsigned short f2bf(float f) {
    union { float f; unsigned int u; } c; c.f = f;
    unsigned int u = c.u;
    return (unsigned short)((u + 0x7FFFu + ((u >> 16) & 1u)) >> 16);  // RNE
}
static __device__ __forceinline__ float uasf(unsigned int u) {
    union { unsigned int u; float f; } c; c.u = u; return c.f;
}

// runtime-counted vmcnt wait (immediate-only instruction -> small switch)
static __device__ __forceinline__ void waitvm(int n) {
    switch (n) {
    case 0: asm volatile("s_waitcnt vmcnt(0)" ::: "memory"); break;
    case 1: asm volatile("s_waitcnt vmcnt(1)" ::: "memory"); break;
    case 2: asm volatile("s_waitcnt vmcnt(2)" ::: "memory"); break;
    case 3: asm volatile("s_waitcnt vmcnt(3)" ::: "memory"); break;
    case 4: asm volatile("s_waitcnt vmcnt(4)" ::: "memory"); break;
    default: asm volatile("s_waitcnt vmcnt(5)" ::: "memory"); break;
    }
    __builtin_amdgcn_sched_barrier(0);
}

// ---------------- phase 1: partition edges into 196 coarse buckets ----------------

__global__ __launch_bounds__(256) void part_kernel(const int* __restrict__ src,
                                                   const int* __restrict__ dst,
                                                   int* __restrict__ gcnt,
                                                   unsigned int* __restrict__ gbuk) {
    __shared__ int hist[NBUK];
    __shared__ int lofs[NBUK];          // exclusive offsets in sorted[]
    __shared__ int gbase[NBUK];         // this block's reservation in bucket region
    __shared__ int sbuf[256];
    __shared__ unsigned int sorted[EPB];
    __shared__ unsigned char bid[EPB];

    const int t  = threadIdx.x;
    const int e0 = blockIdx.x * EPB;
    int ec = N_EDGES - e0; if (ec > EPB) ec = EPB;

    for (int i = t; i < NBUK; i += 256) hist[i] = 0;
    __syncthreads();

    unsigned int rec[16];
    int bb[16], idx[16];
#pragma unroll
    for (int j = 0; j < 16; ++j) {
        int i = j * 256 + t;
        if (i < ec) {
            int s = src[e0 + i], d = dst[e0 + i];
            int b = s >> 8;
            rec[j] = ((unsigned int)(s & 255) << 16) | (unsigned int)d;
            bb[j]  = b;
            idx[j] = atomicAdd(&hist[b], 1);
        } else bb[j] = -1;
    }
    __syncthreads();

    // inclusive scan of hist over 256 slots (entries >= NBUK are 0)
    int v = (t < NBUK) ? hist[t] : 0;
    sbuf[t] = v;
    __syncthreads();
#pragma unroll
    for (int off = 1; off < 256; off <<= 1) {
        int x = (t >= off) ? sbuf[t - off] : 0;
        __syncthreads();
        sbuf[t] += x;
        __syncthreads();
    }
    if (t < NBUK) {
        lofs[t]  = sbuf[t] - v;                 // exclusive
        gbase[t] = atomicAdd(&gcnt[t], v);      // one global atomic per bucket per block
    }
    __syncthreads();

#pragma unroll
    for (int j = 0; j < 16; ++j) {
        if (bb[j] >= 0) {
            int p = lofs[bb[j]] + idx[j];
            sorted[p] = rec[j];
            bid[p] = (unsigned char)bb[j];
        }
    }
    __syncthreads();

    for (int i = t; i < ec; i += 256) {
        int b = bid[i];
        int p = gbase[b] + (i - lofs[b]);
        gbuk[(size_t)b * MAXB + p] = sorted[i];
    }
}

// ---------------- phase 2: per-bucket LDS counting sort -> per-node padded lists ----------------

__global__ __launch_bounds__(256) void sort_kernel(const int* __restrict__ gcnt,
                                                   const unsigned int* __restrict__ gbuk,
                                                   unsigned short* __restrict__ sdst,
                                                   int* __restrict__ deg) {
    __shared__ int hist[256];
    __shared__ int nofs[256];           // exclusive offsets, used as running cursors
    __shared__ int sbuf[256];
    __shared__ unsigned short list[MAXB];

    const int t = threadIdx.x;
    const int b = blockIdx.x;
    const int cnt = gcnt[b];
    const unsigned int* buk = gbuk + (size_t)b * MAXB;

    hist[t] = 0;
    __syncthreads();
    for (int i = t; i < cnt; i += 256)
        atomicAdd(&hist[buk[i] >> 16], 1);
    __syncthreads();

    int v = hist[t];
    sbuf[t] = v;
    __syncthreads();
#pragma unroll
    for (int off = 1; off < 256; off <<= 1) {
        int x = (t >= off) ? sbuf[t - off] : 0;
        __syncthreads();
        sbuf[t] += x;
        __syncthreads();
    }
    nofs[t] = sbuf[t] - v;              // exclusive
    const int n = b * 256 + t;
    if (n < N_NODES) deg[n] = v;
    __syncthreads();

    for (int i = t; i < cnt; i += 256) {
        unsigned int r = buk[i];
        int p = atomicAdd(&nofs[r >> 16], 1);
        list[p] = (unsigned short)(r & 0xffffu);
    }
    __syncthreads();

    if (n < N_NODES) {
        int beg = nofs[t] - v;          // nofs is now inclusive end
        unsigned int* out32 = (unsigned int*)(sdst + (size_t)n * SLOT);  // 192B rows, 4B aligned
        int pc = (v + 15) & ~15;        // pad to mult-16 with zero-row index
        for (int j2 = 0; j2 < (pc >> 1); ++j2) {
            unsigned int lo = (2 * j2     < v) ? list[beg + 2 * j2]     : (unsigned int)ZROW;
            unsigned int hi = (2 * j2 + 1 < v) ? list[beg + 2 * j2 + 1] : (unsigned int)ZROW;
            out32[j2] = lo | (hi << 16);
        }
    }
}

// ---------------- weight repack + zero-row init ----------------

__global__ void convw_kernel(const float* __restrict__ W1, const float* __restrict__ W2,
                             unsigned short* __restrict__ Bt1, unsigned short* __restrict__ Bt2,
                             unsigned short* __restrict__ t1, unsigned short* __restrict__ t2) {
    int i = blockIdx.x * 256 + threadIdx.x;
    if (i < 4 * 512 * 64) {                 // W1[h][k][j] -> Bt1[(h*64+j)][k]
        int h = i >> 15;
        int k = (i >> 6) & 511;
        int j = i & 63;
        Bt1[(h * 64 + j) * 512 + k] = f2bf(W1[i]);
    } else if (i < 4 * 512 * 64 + 256 * 64) {
        int r = i - 4 * 512 * 64;           // W2[k][n] -> Bt2[n][k]
        int k = r >> 6;
        int n = r & 63;
        Bt2[n * 256 + k] = f2bf(W2[r]);
    } else {
        int r = i - (4 * 512 * 64 + 256 * 64);
        if (r < 8 * 32) {                   // zero row of each t1 slice
            t1[(size_t)(r >> 5) * ((size_t)NR * 32) + (size_t)ZROW * 32 + (r & 31)] = 0;
        } else if (r < 8 * 32 + 2 * 32) {   // zero row of each t2 slice
            int q = r - 8 * 32;
            t2[(size_t)(q >> 5) * ((size_t)NR * 32) + (size_t)ZROW * 32 + (q & 31)] = 0;
        }
    }
}

// ---------------- GEMM1: t1s[8][NR][32] = slice-major( X[M][512] @ Bt1[256][512]^T ) ----------------
// BM=128, BN=256 (A read once), block=512 (8 waves 2x4), wave tile 64x64, BK=32.

__global__ __launch_bounds__(512) void gemm1_kernel(const float* __restrict__ A,
                                                    const unsigned short* __restrict__ Bt,
                                                    unsigned short* __restrict__ C) {
    constexpr int BM = 128, BK = 32, LDK = 40, K = D_IN, M = N_NODES;
    __shared__ unsigned short As[BM * LDK];   // 10.0 KB
    __shared__ unsigned short Bs[256 * LDK];  // 20.0 KB

    const int tid  = threadIdx.x;
    const int lane = tid & 63;
    const int w    = tid >> 6;
    const int wm   = (w >> 2) * 64;
    const int wn   = (w & 3) * 64;
    const int quad = lane >> 4;
    const int l15  = lane & 15;
    const int bm   = blockIdx.x;

    f32x4 acc[4][4];
#pragma unroll
    for (int mi = 0; mi < 4; ++mi)
#pragma unroll
        for (int ni = 0; ni < 4; ++ni)
            acc[mi][ni] = (f32x4){0.f, 0.f, 0.f, 0.f};

    const int r0 = tid >> 2;      // 0..127
    const int f8 = tid & 3;       // 8-elem chunk within a 32-col row

    for (int k0 = 0; k0 < K; k0 += BK) {
        {   // stage A (128 x 32 fp32 -> bf16), 8 floats per thread
            int grow = bm * BM + r0;
            if (grow >= M) grow = M - 1;
            const float* ap = A + (size_t)grow * K + k0 + f8 * 8;
            f32x4 v0 = *(const f32x4*)ap;
            f32x4 v1 = *(const f32x4*)(ap + 4);
            u32x4 pk;
            pk[0] = (unsigned int)f2bf(v0[0]) | ((unsigned int)f2bf(v0[1]) << 16);
            pk[1] = (unsigned int)f2bf(v0[2]) | ((unsigned int)f2bf(v0[3]) << 16);
            pk[2] = (unsigned int)f2bf(v1[0]) | ((unsigned int)f2bf(v1[1]) << 16);
            pk[3] = (unsigned int)f2bf(v1[2]) | ((unsigned int)f2bf(v1[3]) << 16);
            *(u32x4*)&As[r0 * LDK + f8 * 8] = pk;
        }
        {   // stage B (256 x 32 bf16), two u32x4 per thread
#pragma unroll
            for (int p = 0; p < 2; ++p) {
                int row = p * 128 + r0;
                u32x4 v = *(const u32x4*)(Bt + (size_t)row * K + k0 + f8 * 8);
                *(u32x4*)&Bs[row * LDK + f8 * 8] = v;
            }
        }
        __syncthreads();

        short8 af[4], bfr[4];
#pragma unroll
        for (int mi = 0; mi < 4; ++mi)
            af[mi] = *(const short8*)&As[(wm + mi * 16 + l15) * LDK + quad * 8];
#pragma unroll
        for (int ni = 0; ni < 4; ++ni)
            bfr[ni] = *(const short8*)&Bs[(wn + ni * 16 + l15) * LDK + quad * 8];
#pragma unroll
        for (int mi = 0; mi < 4; ++mi)
#pragma unroll
            for (int ni = 0; ni < 4; ++ni)
                acc[mi][ni] = __builtin_amdgcn_mfma_f32_16x16x32_bf16(af[mi], bfr[ni], acc[mi][ni], 0, 0, 0);
        __syncthreads();
    }

    // epilogue: slice-major store  t1s[col>>5][row][col&31]
#pragma unroll
    for (int mi = 0; mi < 4; ++mi) {
        int row0 = bm * BM + wm + mi * 16 + quad * 4;
#pragma unroll
        for (int ni = 0; ni < 4; ++ni) {
            int col = wn + ni * 16 + l15;
            unsigned short* cp = C + (size_t)(col >> 5) * ((size_t)NR * 32) + (col & 31);
#pragma unroll
            for (int r = 0; r < 4; ++r) {
                int row = row0 + r;
                if (row < M) cp[(size_t)row * 32] = f2bf(acc[mi][ni][r]);
            }
        }
    }
}

// ---------------- GEMM2: t2s[2][NR][32] = slice-major( h[M][256](bf16) @ Bt2[64][256]^T ) ----------------

__global__ __launch_bounds__(256) void gemm2_kernel(const unsigned short* __restrict__ A,
                                                    const unsigned short* __restrict__ Bt,
                                                    unsigned short* __restrict__ C) {
    constexpr int BM = 64, BK = 32, LDK = 40, K = D_H1, M = N_NODES;
    __shared__ unsigned short As[BM * LDK];
    __shared__ unsigned short Bs[64 * LDK];

    const int tid  = threadIdx.x;
    const int lane = tid & 63;
    const int w    = tid >> 6;
    const int wm   = (w >> 1) * 32;
    const int wn   = (w & 1) * 32;
    const int quad = lane >> 4;
    const int l15  = lane & 15;
    const int bm   = blockIdx.x;

    f32x4 acc[2][2];
#pragma unroll
    for (int mi = 0; mi < 2; ++mi)
#pragma unroll
        for (int ni = 0; ni < 2; ++ni)
            acc[mi][ni] = (f32x4){0.f, 0.f, 0.f, 0.f};

    for (int k0 = 0; k0 < K; k0 += BK) {
        {
            int f8 = tid & 3;
            int r0 = tid >> 2;
            int grow = bm * BM + r0;
            if (grow >= M) grow = M - 1;
            u32x4 v = *(const u32x4*)(A + (size_t)grow * K + k0 + f8 * 8);
            *(u32x4*)&As[r0 * LDK + f8 * 8] = v;
        }
        {
            int f8 = tid & 3;
            int r0 = tid >> 2;
            u32x4 v = *(const u32x4*)(Bt + (size_t)r0 * K + k0 + f8 * 8);
            *(u32x4*)&Bs[r0 * LDK + f8 * 8] = v;
        }
        __syncthreads();

        short8 af[2], bfr[2];
#pragma unroll
        for (int mi = 0; mi < 2; ++mi)
            af[mi] = *(const short8*)&As[(wm + mi * 16 + l15) * LDK + quad * 8];
#pragma unroll
        for (int ni = 0; ni < 2; ++ni)
            bfr[ni] = *(const short8*)&Bs[(wn + ni * 16 + l15) * LDK + quad * 8];
#pragma unroll
        for (int mi = 0; mi < 2; ++mi)
#pragma unroll
            for (int ni = 0; ni < 2; ++ni)
                acc[mi][ni] = __builtin_amdgcn_mfma_f32_16x16x32_bf16(af[mi], bfr[ni], acc[mi][ni], 0, 0, 0);
        __syncthreads();
    }

#pragma unroll
    for (int mi = 0; mi < 2; ++mi) {
        int row0 = bm * BM + wm + mi * 16 + quad * 4;
#pragma unroll
        for (int ni = 0; ni < 2; ++ni) {
            int col = wn + ni * 16 + l15;
            unsigned short* cp = C + (size_t)(col >> 5) * ((size_t)NR * 32) + (col & 31);
#pragma unroll
            for (int r = 0; r < 4; ++r) {
                int row = row0 + r;
                if (row < M) cp[(size_t)row * 32] = f2bf(acc[mi][ni][r]);
            }
        }
    }
}

// ---------------- aggregation: XCD-pinned slices + pipelined 1KB DMA gathers ----------------
// Proven so far: slice pinning (FETCH 346->52 MB, R1) and DMA gather > per-lane gather
// (159->120 us, R3). This round: (a) size-16 DMAs stage 16 rows (1 KB) per instruction,
// so K<=4 issues/node (lists padded to mult-16 with ZROW); (b) 2-buffer cross-node
// pipeline with counted vmcnt -- L2 latency hides under the previous node's consume.
// LDS ring: 4 waves x 2 bufs x 4 KB = 32 KB/block.
//
// DMA slot layout (1 KB): DMA lane l writes row (l>>2), 16B chunk (l&3).
// Consume: lane l reads u32 column (l&15) of rows (l>>4)+4q, q=0..3 (2-way LDS
// aliasing = free), then shfl_xor 16/32 reduces the 4 row-groups.

#define AGG_ISSUE(J, B)                                                                 \
    for (int k = 0; k < K##J; ++k) {                                                    \
        int row = __shfl(elv##J, (k << 4) + (lane >> 2));                               \
        __builtin_amdgcn_global_load_lds(                                               \
            (GASV*)(tb32 + ((unsigned)row << 4) + ((lane & 3) << 2)),                   \
            (LASV*)(&ring[w][B][k << 8]), 16, 0, 0);                                    \
    }

#define AGG_CONSUME(J, B)                                                               \
    {                                                                                   \
        f32x2 Acc = {0.f, 0.f};                                                         \
        for (int k = 0; k < K##J; ++k) {                                                \
            const unsigned int* rb = &ring[w][B][k << 8];                               \
            unsigned int v0 = rb[((lane >> 4)     ) * 16 + (lane & 15)];                \
            unsigned int v1 = rb[((lane >> 4) +  4) * 16 + (lane & 15)];                \
            unsigned int v2 = rb[((lane >> 4) +  8) * 16 + (lane & 15)];                \
            unsigned int v3 = rb[((lane >> 4) + 12) * 16 + (lane & 15)];                \
            Acc.x += uasf(v0 << 16);          Acc.y += uasf(v0 & 0xffff0000u);          \
            Acc.x += uasf(v1 << 16);          Acc.y += uasf(v1 & 0xffff0000u);          \
            Acc.x += uasf(v2 << 16);          Acc.y += uasf(v2 & 0xffff0000u);          \
            Acc.x += uasf(v3 << 16);          Acc.y += uasf(v3 & 0xffff0000u);          \
        }                                                                               \
        f32x2 Bv;                                                                       \
        Bv.x = __shfl_xor(Acc.x, 16); Bv.y = __shfl_xor(Acc.y, 16); Acc += Bv;          \
        Bv.x = __shfl_xor(Acc.x, 32); Bv.y = __shfl_xor(Acc.y, 32); Acc += Bv;          \
        if (lane < 16) {                                                                \
            float iv = (end##J > 0) ? (1.0f / (float)end##J) : 0.f;                     \
            float m0 = Acc.x * iv, m1 = Acc.y * iv;                                     \
            if (ELU) {                                                                  \
                m0 = (m0 > 0.f) ? m0 : (__expf(m0) - 1.f);                              \
                m1 = (m1 > 0.f) ? m1 : (__expf(m1) - 1.f);                              \
                unsigned int pk;                                                        \
                asm("v_cvt_pk_bf16_f32 %0, %1, %2" : "=v"(pk) : "v"(m0), "v"(m1));      \
                *(unsigned int*)&hout[(size_t)(s0 + J) * D_H1 + slice * 32 + (lane & 15) * 2] = pk; \
            } else {                                                                    \
                f32x2 r; r.x = m0; r.y = m1;                                            \
                *(f32x2*)(fout + (size_t)(s0 + J) * D_OUT + slice * 32 + (lane & 15) * 2) = r; \
            }                                                                           \
        }                                                                               \
        __builtin_amdgcn_sched_barrier(0);                                              \
    }

template<int LOGS, bool ELU>
__global__ __launch_bounds__(256) void agg_kernel(const unsigned short* __restrict__ t,
                                                  const int* __restrict__ deg,
                                                  const unsigned short* __restrict__ sdst,
                                                  unsigned short* __restrict__ hout,
                                                  float* __restrict__ fout) {
    __shared__ __align__(16) unsigned int ring[4][2][4 * 256];   // 32 KB
    const int bi    = blockIdx.x;
    const int slice = bi & ((1 << LOGS) - 1);
    const int g     = bi >> LOGS;
    const int w     = __builtin_amdgcn_readfirstlane(threadIdx.x >> 6);
    const int lane  = threadIdx.x & 63;
    const unsigned int* tb32 = (const unsigned int*)t + (size_t)slice * ((size_t)NR * 16);

    const int s0 = g * 16 + w * 4;
    const int end0 = deg[s0 + 0], end1 = deg[s0 + 1], end2 = deg[s0 + 2], end3 = deg[s0 + 3];
    const int elv0 = sdst[(size_t)(s0 + 0) * SLOT + lane];
    const int elv1 = sdst[(size_t)(s0 + 1) * SLOT + lane];
    const int elv2 = sdst[(size_t)(s0 + 2) * SLOT + lane];
    const int elv3 = sdst[(size_t)(s0 + 3) * SLOT + lane];
    const int K0 = ((end0 + 15) & ~15) >> 4;
    const int K1 = ((end1 + 15) & ~15) >> 4;
    const int K2 = ((end2 + 15) & ~15) >> 4;
    const int K3 = ((end3 + 15) & ~15) >> 4;

    AGG_ISSUE(0, 0);
    AGG_ISSUE(1, 1); waitvm(K1);          // node0 landed (K1 newest still allowed in flight)
    AGG_CONSUME(0, 0);                    // ends with 1 global store
    AGG_ISSUE(2, 0); waitvm(K2 + 1);      // +1: store(0) may still be outstanding
    AGG_CONSUME(1, 1);
    AGG_ISSUE(3, 1); waitvm(K3 + 1);
    AGG_CONSUME(2, 0);
    waitvm(1);                            // node3 loads done (store(2) may remain)
    AGG_CONSUME(3, 1);
}

// ---------------- launch ----------------

extern "C" void kernel_launch(void* const* d_in, const int* in_sizes, int n_in,
                              void* d_out, int out_size, void* d_ws, size_t ws_size,
                              hipStream_t stream) {
    const float* X  = (const float*)d_in[0];
    const int*   ei = (const int*)d_in[1];
    const float* W1 = (const float*)d_in[2];
    const float* W2 = (const float*)d_in[3];
    const int* src = ei;             // edge_index[0] = segment ids
    const int* dst = ei + N_EDGES;   // edge_index[1] = gathered neighbors

    char* ws = (char*)d_ws;
    size_t off = 0;
    auto alloc = [&](size_t bytes) {
        off = (off + 255) & ~(size_t)255;
        void* p = ws + off;
        off += bytes;
        return p;
    };
    int*          gcnt = (int*)alloc((size_t)NBUK * 4);
    unsigned int* gbuk = (unsigned int*)alloc((size_t)NBUK * MAXB * 4);
    unsigned short* sdst = (unsigned short*)alloc(((size_t)N_NODES * SLOT + 64) * 2);
    int*          deg  = (int*)alloc((size_t)N_NODES * 4);
    unsigned short* Bt1 = (unsigned short*)alloc((size_t)D_H1 * D_IN * 2);
    unsigned short* Bt2 = (unsigned short*)alloc((size_t)D_OUT * D_H1 * 2);
    unsigned short* t1  = (unsigned short*)alloc((size_t)8 * NR * 32 * 2);
    unsigned short* h   = (unsigned short*)alloc((size_t)N_NODES * D_H1 * 2);
    unsigned short* t2  = (unsigned short*)alloc((size_t)2 * NR * 32 * 2);

    hipMemsetAsync(gcnt, 0, (size_t)NBUK * 4, stream);

    part_kernel<<<NPB, 256, 0, stream>>>(src, dst, gcnt, gbuk);
    sort_kernel<<<NBUK, 256, 0, stream>>>(gcnt, gbuk, sdst, deg);
    convw_kernel<<<(4 * 512 * 64 + 256 * 64 + 8 * 32 + 2 * 32 + 255) / 256, 256, 0, stream>>>(
        W1, W2, Bt1, Bt2, t1, t2);

    gemm1_kernel<<<(N_NODES + 127) / 128, 512, 0, stream>>>(X, Bt1, t1);
    agg_kernel<3, true><<<(N_NODES / 16) * 8, 256, 0, stream>>>(t1, deg, sdst, h, nullptr);
    gemm2_kernel<<<(N_NODES + 63) / 64, 256, 0, stream>>>(h, Bt2, t2);
    agg_kernel<1, false><<<(N_NODES / 16) * 2, 256, 0, stream>>>(t2, deg, sdst, nullptr, (float*)d_out);
}